// Round 8
// baseline (5745.877 us; speedup 1.0000x reference)
//
#include <hip/hip_runtime.h>
#include <cmath>

// RNN: T=2048, B=64, I=H=512, fp32 in/out.
// Phase 0: w_prep  — pre-convert streamed half of W_hh (chunks 8..15) to f16
//                    fragment layout in d_ws (256 KB, L2-resident).
// Phase 1: xw_gemm — f16-MFMA GEMM: xw = x @ W_ih^T + (b_ih+b_hh) -> d_out.
// Phase 2: rnn_scan — 64 WGs (1/batch) x 512 thr, MFMA GEMV (replicated A):
//   chunks 0..7 AGPR-resident; chunks 8..15 streamed per step from d_ws (L2)
//   on the VMEM pipe with grouped prefetch. LDS serves ONLY A-frags (h) ->
//   LDS pipe off the critical path. ONE barrier/step, h triple-buffered.

#define SEQ_T 2048
#define BATCH 64
#define KDIM 512
#define HDIM 512

typedef __fp16 h2v __attribute__((ext_vector_type(2)));
typedef __fp16 f16x8 __attribute__((ext_vector_type(8)));
typedef float f32x4 __attribute__((ext_vector_type(4)));

static __device__ __forceinline__ f16x8 pk8(float4 a, float4 b) {
  h2v p0 = __builtin_amdgcn_cvt_pkrtz(a.x, a.y);
  h2v p1 = __builtin_amdgcn_cvt_pkrtz(a.z, a.w);
  h2v p2 = __builtin_amdgcn_cvt_pkrtz(b.x, b.y);
  h2v p3 = __builtin_amdgcn_cvt_pkrtz(b.z, b.w);
  f16x8 r;
  r[0] = p0[0]; r[1] = p0[1]; r[2] = p1[0]; r[3] = p1[1];
  r[4] = p2[0]; r[5] = p2[1]; r[6] = p3[0]; r[7] = p3[1];
  return r;
}

// ================= Phase 0: prep streamed-W f16 fragment table ==============
// frag(n=8..15, c=0..3, w=0..7, l=0..63) = W[64w+16c+(l&15)][32n+8(l>>4)+e]
// ws index = ((n-8)*4 + c)*512 + w*64 + l   (f16x8 units, 16 B each)
__global__ __launch_bounds__(256) void w_prep(const float* __restrict__ Whh,
                                              f16x8* __restrict__ ws) {
  int v = blockIdx.x * 256 + threadIdx.x;  // 16384
  int l = v & 63, w = (v >> 6) & 7, c = (v >> 9) & 3, n = (v >> 11) + 8;
  int row = 64 * w + 16 * c + (l & 15);
  int col = 32 * n + 8 * (l >> 4);
  const float* p = Whh + (size_t)row * KDIM + col;
  ws[v] = pk8(*(const float4*)p, *(const float4*)(p + 4));
}

// ================= Phase 1: f16 MFMA GEMM ===================================
#define G_LDA 72  // f16 units per row (144 B)

#define MFM(mt, nt) \
  d##mt##nt = __builtin_amdgcn_mfma_f32_16x16x32_f16(fa##mt, fb##nt, d##mt##nt, 0, 0, 0);

#define EPI(mt, nt, bb)                                                     \
  {                                                                         \
    int row = m0 + wm + mt * 16 + (l >> 4) * 4;                             \
    int col = n0 + wn + nt * 16 + (l & 15);                                 \
    out[(size_t)(row + 0) * HDIM + col] = d##mt##nt[0] + bb;                \
    out[(size_t)(row + 1) * HDIM + col] = d##mt##nt[1] + bb;                \
    out[(size_t)(row + 2) * HDIM + col] = d##mt##nt[2] + bb;                \
    out[(size_t)(row + 3) * HDIM + col] = d##mt##nt[3] + bb;                \
  }

__global__ __launch_bounds__(256) void xw_gemm(const float* __restrict__ x,
                                               const float* __restrict__ Wih,
                                               const float* __restrict__ bih,
                                               const float* __restrict__ bhh,
                                               float* __restrict__ out) {
  __shared__ __fp16 At[128 * G_LDA];
  __shared__ __fp16 Bt[64 * G_LDA];
  const int tid = threadIdx.x;
  const int l = tid & 63;
  const int w = tid >> 6;
  const int m0 = (blockIdx.x >> 3) * 128;
  const int n0 = (blockIdx.x & 7) * 64;
  const int wm = (w >> 1) * 64;
  const int wn = (w & 1) * 32;

  const float bias0 = bih[n0 + wn + (l & 15)] + bhh[n0 + wn + (l & 15)];
  const float bias1 = bih[n0 + wn + 16 + (l & 15)] + bhh[n0 + wn + 16 + (l & 15)];

  f32x4 d00 = {0,0,0,0}, d01 = {0,0,0,0}, d10 = {0,0,0,0}, d11 = {0,0,0,0};
  f32x4 d20 = {0,0,0,0}, d21 = {0,0,0,0}, d30 = {0,0,0,0}, d31 = {0,0,0,0};

  for (int k0 = 0; k0 < KDIM; k0 += 64) {
    __syncthreads();
#pragma unroll
    for (int p = 0; p < 4; ++p) {
      int idx = tid + p * 256;
      int r = idx >> 3, sg = idx & 7;
      const float* ps = x + (size_t)(m0 + r) * KDIM + k0 + sg * 8;
      *(f16x8*)(At + r * G_LDA + sg * 8) =
          pk8(*(const float4*)ps, *(const float4*)(ps + 4));
    }
#pragma unroll
    for (int p = 0; p < 2; ++p) {
      int idx = tid + p * 256;
      int r = idx >> 3, sg = idx & 7;
      const float* ps = Wih + (size_t)(n0 + r) * KDIM + k0 + sg * 8;
      *(f16x8*)(Bt + r * G_LDA + sg * 8) =
          pk8(*(const float4*)ps, *(const float4*)(ps + 4));
    }
    __syncthreads();
#pragma unroll
    for (int kk = 0; kk < 2; ++kk) {
      const int kc = kk * 32 + (l >> 4) * 8;
      f16x8 fa0 = *(const f16x8*)(At + (wm + 0 * 16 + (l & 15)) * G_LDA + kc);
      f16x8 fa1 = *(const f16x8*)(At + (wm + 1 * 16 + (l & 15)) * G_LDA + kc);
      f16x8 fa2 = *(const f16x8*)(At + (wm + 2 * 16 + (l & 15)) * G_LDA + kc);
      f16x8 fa3 = *(const f16x8*)(At + (wm + 3 * 16 + (l & 15)) * G_LDA + kc);
      f16x8 fb0 = *(const f16x8*)(Bt + (wn + 0 * 16 + (l & 15)) * G_LDA + kc);
      f16x8 fb1 = *(const f16x8*)(Bt + (wn + 1 * 16 + (l & 15)) * G_LDA + kc);
      MFM(0, 0) MFM(1, 0) MFM(2, 0) MFM(3, 0)
      MFM(0, 1) MFM(1, 1) MFM(2, 1) MFM(3, 1)
    }
  }

  EPI(0, 0, bias0) EPI(1, 0, bias0) EPI(2, 0, bias0) EPI(3, 0, bias0)
  EPI(0, 1, bias1) EPI(1, 1, bias1) EPI(2, 1, bias1) EPI(3, 1, bias1)
}

// ================= Phase 2: MFMA recurrence =================================
// wave w owns rows [64w, 64w+64). B-frag(c,n): W[64w+16c+(l&15)][32n+8(l>>4)+e].
// A-frag(n): h[32n+8gh+e] replicated over rows -> D rows identical.
// Chunks 0..7: AGPR-resident (loaded once, fp32->f16). Chunks 8..15: streamed
// per step from ws (f16, L2-resident), grouped prefetch on VMEM pipe.

#define REPB(M, c) M(c,0) M(c,1) M(c,2) M(c,3) M(c,4) M(c,5) M(c,6) M(c,7)

#define DECLB(c, n) f16x8 bf##c##_##n;
#define LOADB(c, n)                                        \
  {                                                        \
    const float* p = wr##c + 32 * n;                       \
    bf##c##_##n = pk8(*(const float4*)p, *(const float4*)(p + 4)); \
  }

#define DECLS(n) f16x8 sv0_##n, sv1_##n, sv2_##n, sv3_##n;
#define LOADS(n)                                  \
  sv0_##n = wsp[((n - 8) * 4 + 0) * 512];         \
  sv1_##n = wsp[((n - 8) * 4 + 1) * 512];         \
  sv2_##n = wsp[((n - 8) * 4 + 2) * 512];         \
  sv3_##n = wsp[((n - 8) * 4 + 3) * 512];

#define MF(c, n) \
  d##c = __builtin_amdgcn_mfma_f32_16x16x32_f16(acur, bf##c##_##n, d##c, 0, 0, 0);
#define MS(c, n) \
  d##c = __builtin_amdgcn_mfma_f32_16x16x32_f16(acur, sv##c##_##n, d##c, 0, 0, 0);

#define CH(n, nn)                                                \
  {                                                              \
    f16x8 anx = *(const f16x8*)(hcv + 64 * (nn) + goff);         \
    MF(0, n) MF(1, n) MF(2, n) MF(3, n)                          \
    acur = anx;                                                  \
  }
#define CST(n, nn)                                               \
  {                                                              \
    f16x8 anx = *(const f16x8*)(hcv + 64 * (nn) + goff);         \
    MS(0, n) MS(1, n) MS(2, n) MS(3, n)                          \
    acur = anx;                                                  \
  }

__global__ __attribute__((amdgpu_flat_work_group_size(512, 512),
                          amdgpu_waves_per_eu(2, 2)))
void rnn_scan(const float* __restrict__ Whh, const f16x8* __restrict__ ws,
              float* __restrict__ io) {
  __shared__ __align__(16) char ldsm[3 * 1024];
  const int tid = threadIdx.x;
  const int b = blockIdx.x;
  const int l = tid & 63;
  const int w = tid >> 6;
  const int m16 = l & 15;
  const int gh = l >> 4;
  const int goff = gh << 4;
  const int rb = w << 6;
  const int jo = rb + l;

  const float* wr0 = Whh + (size_t)(rb + 0 + m16) * KDIM + 8 * gh;
  const float* wr1 = Whh + (size_t)(rb + 16 + m16) * KDIM + 8 * gh;
  const float* wr2 = Whh + (size_t)(rb + 32 + m16) * KDIM + 8 * gh;
  const float* wr3 = Whh + (size_t)(rb + 48 + m16) * KDIM + 8 * gh;

  // chunks 0..7 resident (AGPR side of the unified file)
  REPB(DECLB, 0) REPB(DECLB, 1) REPB(DECLB, 2) REPB(DECLB, 3)
  REPB(LOADB, 0) REPB(LOADB, 1) REPB(LOADB, 2) REPB(LOADB, 3)

  const f16x8* wsp = ws + (w * 64 + l);

  if (tid < 512) ((unsigned short*)ldsm)[tid] = 0;
  __syncthreads();

  char* hcur = ldsm;
  char* hnxt = ldsm + 1024;
  char* hthr = ldsm + 2048;

  float* iorow = io + (size_t)b * HDIM;

  DECLS(8) DECLS(9) DECLS(10) DECLS(11)
  DECLS(12) DECLS(13) DECLS(14) DECLS(15)

  for (int t = 0; t < SEQ_T; ++t) {
    float uin = iorow[jo];  // HBM prefetch; consumed in tail

    const char* hcv = hcur;
    f16x8 acur = *(const f16x8*)(hcv + goff);

    f32x4 d0 = {0.f, 0.f, 0.f, 0.f};
    f32x4 d1 = {0.f, 0.f, 0.f, 0.f};
    f32x4 d2 = {0.f, 0.f, 0.f, 0.f};
    f32x4 d3 = {0.f, 0.f, 0.f, 0.f};

    LOADS(8) LOADS(9)          // group 0 in flight
    CH(0, 1) CH(1, 2) CH(2, 3)
    LOADS(10) LOADS(11)        // group 1
    CH(3, 4) CH(4, 5) CH(5, 6)
    LOADS(12) LOADS(13)        // group 2
    CH(6, 7) CH(7, 8)
    CST(8, 9) CST(9, 10)       // consume group 0
    LOADS(14) LOADS(15)        // group 3
    CST(10, 11) CST(11, 12)    // consume group 1
    CST(12, 13) CST(13, 14)    // group 2
    CST(14, 15) CST(15, 15)    // group 3

    float za = (l & 16) ? d1[0] : d0[0];
    float zb = (l & 16) ? d3[0] : d2[0];
    float zs = (l & 32) ? zb : za;

    float z = uin + zs;
    float e = __expf(2.0f * z);
    float hn = 1.0f - 2.0f * __builtin_amdgcn_rcpf(e + 1.0f);  // tanh(z)
    iorow[jo] = hn;
    *(__fp16*)(hnxt + 2 * jo) = (__fp16)hn;

    char* tmp = hcur;
    hcur = hnxt; hnxt = hthr; hthr = tmp;
    iorow += (size_t)BATCH * HDIM;
    __syncthreads();
  }
}

extern "C" void kernel_launch(void* const* d_in, const int* in_sizes, int n_in,
                              void* d_out, int out_size, void* d_ws, size_t ws_size,
                              hipStream_t stream) {
  const float* x = (const float*)d_in[0];
  const float* Wih = (const float*)d_in[1];
  const float* Whh = (const float*)d_in[2];
  const float* bih = (const float*)d_in[3];
  const float* bhh = (const float*)d_in[4];
  float* out = (float*)d_out;
  f16x8* ws = (f16x8*)d_ws;

  w_prep<<<64, 256, 0, stream>>>(Whh, ws);

  const int M = SEQ_T * BATCH;
  dim3 g1((M / 128) * (HDIM / 64));  // 8192
  xw_gemm<<<g1, 256, 0, stream>>>(x, Wih, bih, bhh, out);

  rnn_scan<<<BATCH, 512, 0, stream>>>(Whh, ws, out);
}

// Round 9
// 3526.369 us; speedup vs baseline: 1.6294x; 1.6294x over previous
//
#include <hip/hip_runtime.h>
#include <cmath>

// RNN: T=2048, B=64, I=H=512, fp32 in/out.
// Phase 0: w_prep  — pre-convert W_hh chunks 12..15 to f16 frag table in d_ws.
// Phase 1: xw_gemm — f16-MFMA GEMM: xw = x @ W_ih^T + (b_ih+b_hh) -> d_out.
// Phase 2: rnn_scan — 64 WGs (1/batch) x 512 thr, MFMA GEMV (replicated A):
//   W split per the per-CU W-pass budget: 8 chunks AGPR-resident (256 KB),
//   4 chunks LDS (128 KB @128B/cy), 4 chunks streamed from L2 (128 KB @64B/cy)
//   with loads issued at step top, consumed last. lgkm-only barrier (no vmcnt
//   drain). h triple-buffered fp16 in LDS, ONE barrier/step.

#define SEQ_T 2048
#define BATCH 64
#define KDIM 512
#define HDIM 512

typedef __fp16 h2v __attribute__((ext_vector_type(2)));
typedef __fp16 f16x8 __attribute__((ext_vector_type(8)));
typedef float f32x4 __attribute__((ext_vector_type(4)));

static __device__ __forceinline__ f16x8 pk8(float4 a, float4 b) {
  h2v p0 = __builtin_amdgcn_cvt_pkrtz(a.x, a.y);
  h2v p1 = __builtin_amdgcn_cvt_pkrtz(a.z, a.w);
  h2v p2 = __builtin_amdgcn_cvt_pkrtz(b.x, b.y);
  h2v p3 = __builtin_amdgcn_cvt_pkrtz(b.z, b.w);
  f16x8 r;
  r[0] = p0[0]; r[1] = p0[1]; r[2] = p1[0]; r[3] = p1[1];
  r[4] = p2[0]; r[5] = p2[1]; r[6] = p3[0]; r[7] = p3[1];
  return r;
}

// ================= Phase 0: prep streamed-W f16 fragment table ==============
// frag(n=12..15, c=0..3, w=0..7, l=0..63) = W[64w+16c+(l&15)][32n+8(l>>4)+e]
// ws index = ((n-12)*4 + c)*512 + w*64 + l   (f16x8 units, 16 B each)
__global__ __launch_bounds__(256) void w_prep(const float* __restrict__ Whh,
                                              f16x8* __restrict__ ws) {
  int v = blockIdx.x * 256 + threadIdx.x;  // 8192 total
  int l = v & 63, w = (v >> 6) & 7, c = (v >> 9) & 3, n = (v >> 11) + 12;
  int row = 64 * w + 16 * c + (l & 15);
  int col = 32 * n + 8 * (l >> 4);
  const float* p = Whh + (size_t)row * KDIM + col;
  ws[v] = pk8(*(const float4*)p, *(const float4*)(p + 4));
}

// ================= Phase 1: f16 MFMA GEMM ===================================
#define G_LDA 72  // f16 units per row (144 B)

#define MFM(mt, nt) \
  d##mt##nt = __builtin_amdgcn_mfma_f32_16x16x32_f16(fa##mt, fb##nt, d##mt##nt, 0, 0, 0);

#define EPI(mt, nt, bb)                                                     \
  {                                                                         \
    int row = m0 + wm + mt * 16 + (l >> 4) * 4;                             \
    int col = n0 + wn + nt * 16 + (l & 15);                                 \
    out[(size_t)(row + 0) * HDIM + col] = d##mt##nt[0] + bb;                \
    out[(size_t)(row + 1) * HDIM + col] = d##mt##nt[1] + bb;                \
    out[(size_t)(row + 2) * HDIM + col] = d##mt##nt[2] + bb;                \
    out[(size_t)(row + 3) * HDIM + col] = d##mt##nt[3] + bb;                \
  }

__global__ __launch_bounds__(256) void xw_gemm(const float* __restrict__ x,
                                               const float* __restrict__ Wih,
                                               const float* __restrict__ bih,
                                               const float* __restrict__ bhh,
                                               float* __restrict__ out) {
  __shared__ __fp16 At[128 * G_LDA];
  __shared__ __fp16 Bt[64 * G_LDA];
  const int tid = threadIdx.x;
  const int l = tid & 63;
  const int w = tid >> 6;
  const int m0 = (blockIdx.x >> 3) * 128;
  const int n0 = (blockIdx.x & 7) * 64;
  const int wm = (w >> 1) * 64;
  const int wn = (w & 1) * 32;

  const float bias0 = bih[n0 + wn + (l & 15)] + bhh[n0 + wn + (l & 15)];
  const float bias1 = bih[n0 + wn + 16 + (l & 15)] + bhh[n0 + wn + 16 + (l & 15)];

  f32x4 d00 = {0,0,0,0}, d01 = {0,0,0,0}, d10 = {0,0,0,0}, d11 = {0,0,0,0};
  f32x4 d20 = {0,0,0,0}, d21 = {0,0,0,0}, d30 = {0,0,0,0}, d31 = {0,0,0,0};

  for (int k0 = 0; k0 < KDIM; k0 += 64) {
    __syncthreads();
#pragma unroll
    for (int p = 0; p < 4; ++p) {
      int idx = tid + p * 256;
      int r = idx >> 3, sg = idx & 7;
      const float* ps = x + (size_t)(m0 + r) * KDIM + k0 + sg * 8;
      *(f16x8*)(At + r * G_LDA + sg * 8) =
          pk8(*(const float4*)ps, *(const float4*)(ps + 4));
    }
#pragma unroll
    for (int p = 0; p < 2; ++p) {
      int idx = tid + p * 256;
      int r = idx >> 3, sg = idx & 7;
      const float* ps = Wih + (size_t)(n0 + r) * KDIM + k0 + sg * 8;
      *(f16x8*)(Bt + r * G_LDA + sg * 8) =
          pk8(*(const float4*)ps, *(const float4*)(ps + 4));
    }
    __syncthreads();
#pragma unroll
    for (int kk = 0; kk < 2; ++kk) {
      const int kc = kk * 32 + (l >> 4) * 8;
      f16x8 fa0 = *(const f16x8*)(At + (wm + 0 * 16 + (l & 15)) * G_LDA + kc);
      f16x8 fa1 = *(const f16x8*)(At + (wm + 1 * 16 + (l & 15)) * G_LDA + kc);
      f16x8 fa2 = *(const f16x8*)(At + (wm + 2 * 16 + (l & 15)) * G_LDA + kc);
      f16x8 fa3 = *(const f16x8*)(At + (wm + 3 * 16 + (l & 15)) * G_LDA + kc);
      f16x8 fb0 = *(const f16x8*)(Bt + (wn + 0 * 16 + (l & 15)) * G_LDA + kc);
      f16x8 fb1 = *(const f16x8*)(Bt + (wn + 1 * 16 + (l & 15)) * G_LDA + kc);
      MFM(0, 0) MFM(1, 0) MFM(2, 0) MFM(3, 0)
      MFM(0, 1) MFM(1, 1) MFM(2, 1) MFM(3, 1)
    }
  }

  EPI(0, 0, bias0) EPI(1, 0, bias0) EPI(2, 0, bias0) EPI(3, 0, bias0)
  EPI(0, 1, bias1) EPI(1, 1, bias1) EPI(2, 1, bias1) EPI(3, 1, bias1)
}

// ================= Phase 2: MFMA recurrence =================================
// wave w owns rows [64w, 64w+64). B-frag(c,n): W[64w+16c+(l&15)][32n+8(l>>4)+e].
// A-frag(n): h[32n+8gh+e] replicated over rows -> D rows identical.
// Chunks 0..7: AGPR. Chunks 8..11: LDS. Chunks 12..15: L2 stream (issue top,
// consume last).

#define REPB(M, c) M(c,0) M(c,1) M(c,2) M(c,3) M(c,4) M(c,5) M(c,6) M(c,7)

#define DECLB(c, n) f16x8 bf##c##_##n;
#define LOADB(c, n)                                        \
  {                                                        \
    const float* p = wr##c + 32 * n;                       \
    bf##c##_##n = pk8(*(const float4*)p, *(const float4*)(p + 4)); \
  }
#define STOREB(c, n)                                                        \
  {                                                                         \
    const float* p = wr##c + 32 * n;                                        \
    *(f16x8*)(ldsm + (((n) - 8) * 4 + c) * 8192 + (tid << 4)) =             \
        pk8(*(const float4*)p, *(const float4*)(p + 4));                    \
  }

#define DECLS(n) f16x8 sv0_##n, sv1_##n, sv2_##n, sv3_##n;
#define LOADS(n)                                   \
  sv0_##n = wsp[((n - 12) * 4 + 0) * 512];         \
  sv1_##n = wsp[((n - 12) * 4 + 1) * 512];         \
  sv2_##n = wsp[((n - 12) * 4 + 2) * 512];         \
  sv3_##n = wsp[((n - 12) * 4 + 3) * 512];

#define MF(c, n) \
  d##c = __builtin_amdgcn_mfma_f32_16x16x32_f16(acur, bf##c##_##n, d##c, 0, 0, 0);
#define MFL(c, n)                                                              \
  {                                                                            \
    f16x8 bl = *(const f16x8*)(ldsm + (((n) - 8) * 4 + c) * 8192 + (tid << 4)); \
    d##c = __builtin_amdgcn_mfma_f32_16x16x32_f16(acur, bl, d##c, 0, 0, 0);    \
  }
#define MS(c, n) \
  d##c = __builtin_amdgcn_mfma_f32_16x16x32_f16(acur, sv##c##_##n, d##c, 0, 0, 0);

#define CH(n, nn)                                                \
  {                                                              \
    f16x8 anx = *(const f16x8*)(hcv + 64 * (nn) + goff);         \
    MF(0, n) MF(1, n) MF(2, n) MF(3, n)                          \
    acur = anx;                                                  \
  }
#define CHL(n, nn)                                               \
  {                                                              \
    f16x8 anx = *(const f16x8*)(hcv + 64 * (nn) + goff);         \
    MFL(0, n) MFL(1, n) MFL(2, n) MFL(3, n)                      \
    acur = anx;                                                  \
  }
#define CST(n, nn)                                               \
  {                                                              \
    f16x8 anx = *(const f16x8*)(hcv + 64 * (nn) + goff);         \
    MS(0, n) MS(1, n) MS(2, n) MS(3, n)                          \
    acur = anx;                                                  \
  }

#define WLDS_BYTES (16 * 8192)             // 131072 (chunks 8..11)
#define HBUF0 WLDS_BYTES
#define LDS_TOTAL (WLDS_BYTES + 3 * 1024)  // 134144

// lgkm-only barrier: h-buffer ordering without draining VMEM (stores/prefetch
// stay in flight across steps).
#define BAR()                                              \
  asm volatile("s_waitcnt lgkmcnt(0)" ::: "memory");       \
  __builtin_amdgcn_sched_barrier(0);                       \
  __builtin_amdgcn_s_barrier();                            \
  __builtin_amdgcn_sched_barrier(0);

__global__ __attribute__((amdgpu_flat_work_group_size(512, 512),
                          amdgpu_waves_per_eu(2, 2)))
void rnn_scan(const float* __restrict__ Whh, const f16x8* __restrict__ ws,
              float* __restrict__ io) {
  extern __shared__ __align__(16) char ldsm[];
  const int tid = threadIdx.x;
  const int b = blockIdx.x;
  const int l = tid & 63;
  const int w = tid >> 6;
  const int m16 = l & 15;
  const int gh = l >> 4;
  const int goff = gh << 4;
  const int rb = w << 6;
  const int jo = rb + l;

  const float* wr0 = Whh + (size_t)(rb + 0 + m16) * KDIM + 8 * gh;
  const float* wr1 = Whh + (size_t)(rb + 16 + m16) * KDIM + 8 * gh;
  const float* wr2 = Whh + (size_t)(rb + 32 + m16) * KDIM + 8 * gh;
  const float* wr3 = Whh + (size_t)(rb + 48 + m16) * KDIM + 8 * gh;

  // chunks 0..7 resident (AGPR side of the unified file)
  REPB(DECLB, 0) REPB(DECLB, 1) REPB(DECLB, 2) REPB(DECLB, 3)
  REPB(LOADB, 0) REPB(LOADB, 1) REPB(LOADB, 2) REPB(LOADB, 3)

  // chunks 8..11 in LDS (128 KB)
  STOREB(0, 8)  STOREB(1, 8)  STOREB(2, 8)  STOREB(3, 8)
  STOREB(0, 9)  STOREB(1, 9)  STOREB(2, 9)  STOREB(3, 9)
  STOREB(0, 10) STOREB(1, 10) STOREB(2, 10) STOREB(3, 10)
  STOREB(0, 11) STOREB(1, 11) STOREB(2, 11) STOREB(3, 11)

  const f16x8* wsp = ws + (w * 64 + l);

  if (tid < 512) ((unsigned short*)(ldsm + HBUF0))[tid] = 0;
  __syncthreads();

  char* hcur = ldsm + HBUF0;
  char* hnxt = ldsm + HBUF0 + 1024;
  char* hthr = ldsm + HBUF0 + 2048;

  float* iorow = io + (size_t)b * HDIM;

  DECLS(12) DECLS(13) DECLS(14) DECLS(15)

  for (int t = 0; t < SEQ_T; ++t) {
    float uin = iorow[jo];     // HBM prefetch; consumed in tail

    // issue all streamed-chunk loads NOW; consumed last (max MFMA cover)
    LOADS(12) LOADS(13) LOADS(14) LOADS(15)

    const char* hcv = hcur;
    f16x8 acur = *(const f16x8*)(hcv + goff);

    f32x4 d0 = {0.f, 0.f, 0.f, 0.f};
    f32x4 d1 = {0.f, 0.f, 0.f, 0.f};
    f32x4 d2 = {0.f, 0.f, 0.f, 0.f};
    f32x4 d3 = {0.f, 0.f, 0.f, 0.f};

    CH(0, 1)  CH(1, 2)   CH(2, 3)   CH(3, 4)
    CH(4, 5)  CH(5, 6)   CH(6, 7)   CH(7, 8)
    CHL(8, 9) CHL(9, 10) CHL(10, 11) CHL(11, 12)
    CST(12, 13) CST(13, 14) CST(14, 15) CST(15, 15)

    float za = (l & 16) ? d1[0] : d0[0];
    float zb = (l & 16) ? d3[0] : d2[0];
    float zs = (l & 32) ? zb : za;

    float z = uin + zs;
    float e = __expf(2.0f * z);
    float hn = 1.0f - 2.0f * __builtin_amdgcn_rcpf(e + 1.0f);  // tanh(z)
    iorow[jo] = hn;
    *(__fp16*)(hnxt + 2 * jo) = (__fp16)hn;

    char* tmp = hcur;
    hcur = hnxt; hnxt = hthr; hthr = tmp;
    iorow += (size_t)BATCH * HDIM;
    BAR();
  }
}

extern "C" void kernel_launch(void* const* d_in, const int* in_sizes, int n_in,
                              void* d_out, int out_size, void* d_ws, size_t ws_size,
                              hipStream_t stream) {
  const float* x = (const float*)d_in[0];
  const float* Wih = (const float*)d_in[1];
  const float* Whh = (const float*)d_in[2];
  const float* bih = (const float*)d_in[3];
  const float* bhh = (const float*)d_in[4];
  float* out = (float*)d_out;
  f16x8* ws = (f16x8*)d_ws;

  (void)hipFuncSetAttribute((const void*)rnn_scan,
                            hipFuncAttributeMaxDynamicSharedMemorySize,
                            LDS_TOTAL);

  w_prep<<<32, 256, 0, stream>>>(Whh, ws);

  const int M = SEQ_T * BATCH;
  dim3 g1((M / 128) * (HDIM / 64));  // 8192
  xw_gemm<<<g1, 256, 0, stream>>>(x, Wih, bih, bhh, out);

  rnn_scan<<<BATCH, 512, LDS_TOTAL, stream>>>(Whh, ws, out);
}